// Round 9
// baseline (62.611 us; speedup 1.0000x reference)
//
#include <hip/hip_runtime.h>
#include <math.h>

#define NQ   11
#define DIM  2048        // 2^11
#define NL   6
#define SPB  4           // samples per persistent k2 block

typedef float v2f __attribute__((ext_vector_type(2)));   // (re, im)

// GF(2)-linear swizzles (R3-R8 proven conflict-free for these pattern sets)
__host__ __device__ constexpr int swzA(int x) {
    return x ^ ((x >> 6) & 31) ^ ((x & 2) << 3) ^ ((x & 1) << 3);
}
__host__ __device__ constexpr int swzB(int x) {
    return x ^ ((x >> 7) & 7) ^ ((x >> 3) & 14) ^ ((x >> 6) & 8);
}

// raw barrier: drains LDS only, leaves global stores in flight (the whole
// point of the persistent k2 pipeline — __syncthreads would vmcnt(0)-drain)
#define BAR_LDS() do { \
    asm volatile("s_waitcnt lgkmcnt(0)" ::: "memory"); \
    __builtin_amdgcn_s_barrier(); \
} while (0)

// DPP lane-xor (VALU pipe): 177=xor1, 27=xor3, 0x141=xor7 (R8-verified)
template<int CTRL>
__device__ __forceinline__ v2f dpp_xor(v2f v) {
    const int x = __builtin_amdgcn_update_dpp(
        0, __float_as_int(v.x), CTRL, 0xF, 0xF, true);
    const int y = __builtin_amdgcn_update_dpp(
        0, __float_as_int(v.y), CTRL, 0xF, 0xF, true);
    v2f r; r.x = __int_as_float(x); r.y = __int_as_float(y);
    return r;
}

// packed complex pair rotation: A0' = U00*A0 + U01*A1 ; A1' = U10*A0 + U11*A1
__device__ __forceinline__ void cpair(const v2f U00, const v2f U01,
                                      const v2f U10, const v2f U11,
                                      v2f& A0, v2f& A1) {
    const v2f a0 = A0, a1 = A1;
    const v2f a0i = {-a0.y, a0.x};      // i*a0
    const v2f a1i = {-a1.y, a1.x};      // i*a1
    A0 = U00.x*a0 + U00.y*a0i + U01.x*a1 + U01.y*a1i;   // 4 v_pk_fma chain
    A1 = U10.x*a0 + U10.y*a0i + U11.x*a1 + U11.y*a1i;
}

// ================= kernel 1: all sample-independent work, 1 block ============
// layers 0..4 (gates + CNOT perm) + layer 5 shared RZ·RY·RZ (no perm).
// R5 skeleton; packed math; barriers 6->4 per layer via same-slot elision.
__global__ __launch_bounds__(256) void qnn_shared_kernel(
    const float* __restrict__ P,      // (NL, NQ, 3)
    float2* __restrict__ ws)          // out: 2048 float2, natural order
{
    __shared__ v2f lds[DIM];
    __shared__ v2f G[NL*NQ][4];
    const int t = threadIdx.x;        // 8 bits

    if (t < NL*NQ) {
        const float p0 = P[t*3+0], p1 = P[t*3+1], p2 = P[t*3+2];
        const float th = 0.5f*p1;
        const float c  = cosf(th), s = sinf(th);
        const float al = 0.5f*(p0+p2), be = 0.5f*(p0-p2);
        const float ca = cosf(al), sa = sinf(al);
        const float cb = cosf(be), sb = sinf(be);
        G[t][0] = (v2f){ c*ca, -c*sa};
        G[t][1] = (v2f){-s*cb, -s*sb};
        G[t][2] = (v2f){ s*cb, -s*sb};
        G[t][3] = (v2f){ c*ca,  c*sa};
    }

    const int a0w = swzA(t);                          // X1 write (k<<8)
    const int a1b = swzA(((t>>5)<<8) | (t&31));       // X1 read / X2 write (k<<5)
    const int a2b = swzA(((t>>2)<<5) | (t&3));        // X2 read / X3 write (k<<2)
    const int a3b = swzA(t ^ (t>>1));                 // X3 perm-gather read
    const int natb = ((t>>2)<<5) | (t&3);             // ws natural-order base

    v2f a[8];
    #pragma unroll
    for (int k = 0; k < 8; ++k) a[k] = (v2f){0.f, 0.f};
    if (t == 0) a[0] = (v2f){1.f, 0.f};
    __syncthreads();   // G ready

    #define CG(g_, rb_) { \
        const v2f U00=G[g_][0], U01=G[g_][1], U10=G[g_][2], U11=G[g_][3]; \
        _Pragma("unroll") \
        for (int kk = 0; kk < 8; ++kk) if (!(kk & (rb_))) \
            cpair(U00, U01, U10, U11, a[kk], a[kk|(rb_)]); \
    }

    #define SG(g_, m_, b_) { \
        const v2f ca_ = (b_) ? G[g_][3] : G[g_][0]; \
        const v2f cb_ = (b_) ? G[g_][2] : G[g_][1]; \
        _Pragma("unroll") \
        for (int kk = 0; kk < 8; ++kk) { \
            v2f p; \
            p.x = __shfl_xor(a[kk].x, m_); \
            p.y = __shfl_xor(a[kk].y, m_); \
            const v2f si = {-a[kk].y, a[kk].x}; \
            const v2f pi = {-p.y, p.x}; \
            a[kk] = ca_.x*a[kk] + ca_.y*si + cb_.x*p + cb_.y*pi; \
        } }

    for (int l = 0; l < NL; ++l) {
        const int g0 = l*NQ;
        CG(g0+0, 4) CG(g0+1, 2) CG(g0+2, 1)          // qubits 0,1,2 (bits 10,9,8)

        #pragma unroll
        for (int k = 0; k < 8; ++k) lds[a0w ^ swzA(k<<8)] = a[k];
        __syncthreads();
        #pragma unroll
        for (int k = 0; k < 8; ++k) a[k] = lds[a1b ^ swzA(k<<5)];
        CG(g0+3, 4) CG(g0+4, 2) CG(g0+5, 1)          // qubits 3,4,5 (bits 7,6,5)

        // X2 write: same per-thread slots as X1 read -> no barrier needed
        #pragma unroll
        for (int k = 0; k < 8; ++k) lds[a1b ^ swzA(k<<5)] = a[k];
        __syncthreads();
        #pragma unroll
        for (int k = 0; k < 8; ++k) a[k] = lds[a2b ^ swzA(k<<2)];
        CG(g0+6, 4) CG(g0+7, 2) CG(g0+8, 1)          // qubits 6,7,8 (bits 4,3,2)

        SG(g0+9, 2, (t>>1)&1)                        // qubit 9 (bit 1)
        SG(g0+10, 1, t&1)                            // qubit 10 (bit 0)

        if (l < NL-1) {
            // X3 write: same per-thread slots as X2 read -> no barrier needed
            #pragma unroll
            for (int k = 0; k < 8; ++k) lds[a2b ^ swzA(k<<2)] = a[k];
            __syncthreads();
            #pragma unroll
            for (int k = 0; k < 8; ++k)
                a[k] = lds[a3b ^ swzA((k<<8) ^ (k<<7))];   // src = g((k<<8)|t)
            __syncthreads();
        } else {
            #pragma unroll
            for (int k = 0; k < 8; ++k)
                ws[natb | (k<<2)] = make_float2(a[k].x, a[k].y);
        }
    }
    #undef CG
    #undef SG
}

// ===== kernel 2: persistent, SPB samples/block; master state in registers ====
// Per sample: RG(0..3) | X1 | RG(4..7) | X2+perm-gather | DPP gates | store.
// Raw barriers keep stores of sample i in flight during compute of i+1.
__global__ __launch_bounds__(128, 4) void qnn_last_kernel(
    const float* __restrict__ X,      // (B, NQ)
    const float2* __restrict__ S5,    // shared state, natural order
    float2* __restrict__ out,         // (B, DIM)
    const int B)
{
    __shared__ float2 lds[DIM];
    __shared__ float2 gcs[SPB][NQ];
    const int t  = threadIdx.x;       // 7 bits
    const int b0 = blockIdx.x * SPB;
    const int ns = min(SPB, B - b0);

    // one sincos per thread for all the block's samples (no idle-lane bubble)
    if (t < ns*NQ) {
        const int si = t / NQ, q = t - si*NQ;
        const float tx = 0.5f * X[(size_t)(b0+si)*NQ + q];
        gcs[si][q] = make_float2(cosf(tx), sinf(tx));
    }

    // swizzled per-thread LDS bases (GF(2)-linear: base ^ constexpr k-part)
    const int w0 = swzB(t);                           // X1 write  (k<<7)
    const int w1 = swzB(((t>>3)<<7) | (t&7));         // X1 read / X2 write (k<<3)
    const int w3 = swzB(t ^ (t>>1));                  // X2 perm-gather read

    // master state: reg k holds amp i = (k<<7)|t, loaded ONCE
    v2f m[16];
    #pragma unroll
    for (int k = 0; k < 16; ++k) {
        const float2 v = S5[(k<<7) | t];
        m[k] = (v2f){v.x, v.y};
    }
    __syncthreads();   // gcs ready (stores: none in flight yet)

    #define RG(q_, rb_) { \
        const float c = gcs[s][q_].x, sn = gcs[s][q_].y; \
        _Pragma("unroll") \
        for (int kk = 0; kk < 16; ++kk) if (!(kk & (rb_))) { \
            const v2f a0 = a[kk], a1 = a[kk|(rb_)]; \
            a[kk]       = c*a0 - sn*a1; \
            a[kk|(rb_)] = sn*a0 + c*a1; \
        } }

    #define LGD(q_, CTRL_, r_) { \
        const float c = gcs[s][q_].x, sn = gcs[s][q_].y; \
        const float sg = (r_) ? sn : -sn; \
        _Pragma("unroll") \
        for (int kk = 0; kk < 16; ++kk) { \
            const v2f p = dpp_xor<CTRL_>(a[kk]); \
            a[kk] = c*a[kk] + sg*p; \
        } }

    for (int s = 0; s < ns; ++s) {
        v2f a[16];
        // qubit 0 (bit 10) applied straight from the master copy (fused copy)
        {
            const float c = gcs[s][0].x, sn = gcs[s][0].y;
            #pragma unroll
            for (int kk = 0; kk < 8; ++kk) {
                a[kk]   = c*m[kk] - sn*m[kk|8];
                a[kk|8] = sn*m[kk] + c*m[kk|8];
            }
        }
        RG(1, 4) RG(2, 2) RG(3, 1)                   // qubits 1..3 (bits 9..7)

        // X1 -> L1: i = (t[6:3]<<7)|(k<<3)|t[2:0]
        #pragma unroll
        for (int k = 0; k < 16; ++k)
            lds[w0 ^ swzB(k<<7)] = make_float2(a[k].x, a[k].y);
        BAR_LDS();
        #pragma unroll
        for (int k = 0; k < 16; ++k) {
            const float2 v = lds[w1 ^ swzB(k<<3)];
            a[k] = (v2f){v.x, v.y};
        }
        RG(4, 8) RG(5, 4) RG(6, 2) RG(7, 1)          // qubits 4..7 (bits 6..3)

        // X2 write: same per-thread slots as X1 read -> no barrier before
        #pragma unroll
        for (int k = 0; k < 16; ++k)
            lds[w1 ^ swzB(k<<3)] = make_float2(a[k].x, a[k].y);
        BAR_LDS();
        // perm-fold gather: a[k] = S[g(o)], o = (k<<7)|t, g(o)=o^(o>>1)
        #pragma unroll
        for (int k = 0; k < 16; ++k) {
            const float2 v = lds[w3 ^ swzB((k<<7) ^ (k<<6))];
            a[k] = (v2f){v.x, v.y};
        }

        // remaining gates (state bits 2,1,0) in o-domain via DPP lane-xors
        LGD(8, 0x141, ((t>>2) ^ (t>>3)) & 1)         // xor7, role t2^t3
        LGD(9, 27,    ((t>>1) ^ (t>>2)) & 1)         // xor3, role t1^t2
        LGD(10, 177,  ( t     ^ (t>>1)) & 1)         // xor1, role t0^t1

        // store: 512 B contiguous per wave per k; left in flight across BAR
        float2* o = out + (size_t)(b0+s) * DIM + t;
        #pragma unroll
        for (int k = 0; k < 16; ++k)
            o[k<<7] = make_float2(a[k].x, a[k].y);

        BAR_LDS();   // lds reuse guard (LDS-only drain; stores keep flowing)
    }
    #undef RG
    #undef LGD
}

extern "C" void kernel_launch(void* const* d_in, const int* in_sizes, int n_in,
                              void* d_out, int out_size, void* d_ws, size_t ws_size,
                              hipStream_t stream) {
    const float* X = (const float*)d_in[0];   // (B, NQ) float32
    const float* P = (const float*)d_in[1];   // (NL, NQ, 3) float32
    float2* out = (float2*)d_out;
    float2* ws  = (float2*)d_ws;              // 16 KB shared state
    const int B = in_sizes[0] / NQ;           // 8192
    const int nb = (B + SPB - 1) / SPB;       // 2048 persistent blocks
    qnn_shared_kernel<<<1, 256, 0, stream>>>(P, ws);
    qnn_last_kernel<<<nb, 128, 0, stream>>>(X, ws, out, B);
}

// Round 10
// 52.123 us; speedup vs baseline: 1.2012x; 1.2012x over previous
//
#include <hip/hip_runtime.h>
#include <math.h>

#define NQ   11
#define DIM  2048        // 2^11
#define NL   6

typedef float v2f __attribute__((ext_vector_type(2)));   // (re, im)

// GF(2)-linear swizzle for kernel 1 (R3-R8 proven conflict-free)
__host__ __device__ constexpr int swzA(int x) {
    return x ^ ((x >> 6) & 31) ^ ((x & 2) << 3) ^ ((x & 1) << 3);
}
// h = g^{-1} of the CNOT-chain perm g(o)=o^(o>>1): prefix-XOR from MSB
__host__ __device__ constexpr int hperm(int x) {
    return x ^ (x>>1) ^ (x>>2) ^ (x>>3) ^ (x>>4) ^ (x>>5)
             ^ (x>>6) ^ (x>>7) ^ (x>>8) ^ (x>>9) ^ (x>>10);
}

__device__ __forceinline__ float2 cfma2(float2 u, float2 a, float2 v, float2 b) {
    float2 r;
    r.x = u.x*a.x - u.y*a.y + v.x*b.x - v.y*b.y;
    r.y = u.x*a.y + u.y*a.x + v.x*b.y + v.y*b.x;
    return r;
}

// DPP lane-xor (VALU pipe): 177=xor1, 27=xor3, 0x141=xor7, 0x140=xor15
template<int CTRL>
__device__ __forceinline__ v2f dpp_xor(v2f v) {
    const int x = __builtin_amdgcn_update_dpp(
        0, __float_as_int(v.x), CTRL, 0xF, 0xF, true);
    const int y = __builtin_amdgcn_update_dpp(
        0, __float_as_int(v.y), CTRL, 0xF, 0xF, true);
    v2f r; r.x = __int_as_float(x); r.y = __int_as_float(y);
    return r;
}

// ================= kernel 1: all sample-independent work, 1 block ============
// (byte-for-byte the proven R5/R8 version)
__global__ __launch_bounds__(256) void qnn_shared_kernel(
    const float* __restrict__ P,      // (NL, NQ, 3)
    float2* __restrict__ ws)          // out: 2048 float2, natural order
{
    __shared__ float2 lds[DIM];
    __shared__ float2 G[NL*NQ][4];
    const int t = threadIdx.x;        // 8 bits

    if (t < NL*NQ) {
        const float p0 = P[t*3+0], p1 = P[t*3+1], p2 = P[t*3+2];
        const float th = 0.5f*p1;
        const float c  = cosf(th), s = sinf(th);
        const float al = 0.5f*(p0+p2), be = 0.5f*(p0-p2);
        const float ca = cosf(al), sa = sinf(al);
        const float cb = cosf(be), sb = sinf(be);
        G[t][0] = make_float2( c*ca, -c*sa);
        G[t][1] = make_float2(-s*cb, -s*sb);
        G[t][2] = make_float2( s*cb, -s*sb);
        G[t][3] = make_float2( c*ca,  c*sa);
    }

    const int a0w = swzA(t);                          // X1 write (k<<8)
    const int a1b = swzA(((t>>5)<<8) | (t&31));       // X1 read / X2 write (k<<5)
    const int a2b = swzA(((t>>2)<<5) | (t&3));        // X2 read / X3 write (k<<2)
    const int a3b = swzA(t ^ (t>>1));                 // X3 perm-gather read
    const int natb = ((t>>2)<<5) | (t&3);             // ws natural-order base

    float2 a[8];
    #pragma unroll
    for (int k = 0; k < 8; ++k) a[k] = make_float2(0.f, 0.f);
    if (t == 0) a[0] = make_float2(1.f, 0.f);
    __syncthreads();   // G ready

    #define CG(g_, rb_) { \
        const float2 U00=G[g_][0], U01=G[g_][1], U10=G[g_][2], U11=G[g_][3]; \
        _Pragma("unroll") \
        for (int kk = 0; kk < 8; ++kk) if (!(kk & (rb_))) { \
            const float2 a0 = a[kk], a1 = a[kk|(rb_)]; \
            a[kk]       = cfma2(U00, a0, U01, a1); \
            a[kk|(rb_)] = cfma2(U10, a0, U11, a1); \
        } }

    #define SG(g_, m_, b_) { \
        const float2 ca_ = (b_) ? G[g_][3] : G[g_][0]; \
        const float2 cb_ = (b_) ? G[g_][2] : G[g_][1]; \
        _Pragma("unroll") \
        for (int kk = 0; kk < 8; ++kk) { \
            float2 p; \
            p.x = __shfl_xor(a[kk].x, m_); \
            p.y = __shfl_xor(a[kk].y, m_); \
            a[kk] = cfma2(ca_, a[kk], cb_, p); \
        } }

    for (int l = 0; l < NL; ++l) {
        const int g0 = l*NQ;
        CG(g0+0, 4) CG(g0+1, 2) CG(g0+2, 1)          // qubits 0,1,2 (bits 10,9,8)

        #pragma unroll
        for (int k = 0; k < 8; ++k) lds[a0w ^ swzA(k<<8)] = a[k];
        __syncthreads();
        #pragma unroll
        for (int k = 0; k < 8; ++k) a[k] = lds[a1b ^ swzA(k<<5)];
        __syncthreads();
        CG(g0+3, 4) CG(g0+4, 2) CG(g0+5, 1)          // qubits 3,4,5 (bits 7,6,5)

        #pragma unroll
        for (int k = 0; k < 8; ++k) lds[a1b ^ swzA(k<<5)] = a[k];
        __syncthreads();
        #pragma unroll
        for (int k = 0; k < 8; ++k) a[k] = lds[a2b ^ swzA(k<<2)];
        __syncthreads();
        CG(g0+6, 4) CG(g0+7, 2) CG(g0+8, 1)          // qubits 6,7,8 (bits 4,3,2)

        SG(g0+9, 2, (t>>1)&1)                        // qubit 9 (bit 1)
        SG(g0+10, 1, t&1)                            // qubit 10 (bit 0)

        if (l < NL-1) {
            #pragma unroll
            for (int k = 0; k < 8; ++k) lds[a2b ^ swzA(k<<2)] = a[k];
            __syncthreads();
            #pragma unroll
            for (int k = 0; k < 8; ++k)
                a[k] = lds[a3b ^ swzA((k<<8) ^ (k<<7))];   // src = g((k<<8)|t)
            __syncthreads();
        } else {
            #pragma unroll
            for (int k = 0; k < 8; ++k) ws[natb | (k<<2)] = a[k];
        }
    }
    #undef CG
    #undef SG
}

// ========= kernel 2: cell-paired (float4) layout, 8192 blocks ================
// 128 threads x 8 cells (16 amps). Amp pairs {2c,2c+1} ride together as one
// 16B cell through load / both exchanges / store. CNOT perm h-folded into the
// X2 write; q6..q9 applied post-perm as o-domain DPP butterflies.
__global__ __launch_bounds__(128, 4) void qnn_last_kernel(
    const float* __restrict__ X,      // (B, NQ)
    const float4* __restrict__ S5c,   // shared state, 1024 cells, natural order
    float4* __restrict__ out4)        // (B, 1024) cells
{
    __shared__ float4 ldsc[DIM/2];    // 1024 cells = 16 KB
    __shared__ float2 gc[NQ];
    const int b = blockIdx.x;
    const int t = threadIdx.x;        // 7 bits

    if (t < NQ) {
        const float tx = 0.5f * X[(size_t)b*NQ + t];
        gc[t] = make_float2(cosf(tx), sinf(tx));
    }

    // L0: a[2k+e] = amp s=(k<<8)|(t<<1)|e ; cell (k<<7)|t ; 1KB/wave loads
    v2f a[16];
    #pragma unroll
    for (int k = 0; k < 8; ++k) {
        const float4 v = S5c[(k<<7) | t];
        a[2*k]   = (v2f){v.x, v.y};
        a[2*k+1] = (v2f){v.z, v.w};
    }
    __syncthreads();   // bar1: gc ready

    // packed real RY on a-index bit rb_ (all-vector operands -> v_pk_fma_f32)
    #define RG(q_, rb_) { \
        const float c = gc[q_].x, sn = gc[q_].y; \
        const v2f cc = {c, c}, sv = {sn, sn}; \
        _Pragma("unroll") \
        for (int j = 0; j < 16; ++j) if (!(j & (rb_))) { \
            const v2f a0 = a[j], a1 = a[j|(rb_)]; \
            a[j]       = cc*a0 - sv*a1; \
            a[j|(rb_)] = sv*a0 + cc*a1; \
        } }

    // o-domain conjugated RY: partner = lane-xor (DPP) of e-swapped reg
    #define CGD(q_, CTRL_, r_) { \
        const float c = gc[q_].x, sn = gc[q_].y; \
        const float sg = (r_) ? sn : -sn; \
        const v2f cc = {c, c}, sgv = {sg, sg}; \
        _Pragma("unroll") \
        for (int k = 0; k < 8; ++k) { \
            const v2f o0 = a[2*k], o1 = a[2*k+1]; \
            const v2f p0 = dpp_xor<CTRL_>(o1); \
            const v2f p1 = dpp_xor<CTRL_>(o0); \
            a[2*k]   = cc*o0 + sgv*p0; \
            a[2*k+1] = cc*o1 + sgv*p1; \
        } }

    // S1: reg amp-bits {10,9,8} = k, {0} = e
    RG(0, 8) RG(1, 4) RG(2, 2) RG(10, 1)

    // X1 write: cell (k<<7)|t  (k-part disjoint -> ds imm offset)
    #pragma unroll
    for (int k = 0; k < 8; ++k)
        ldsc[(k<<7) | t] = make_float4(a[2*k].x, a[2*k].y, a[2*k+1].x, a[2*k+1].y);
    __syncthreads();   // bar2
    // X1 read: s = (t[6:4]<<8)|(k<<5)|(t[3:1]<<2)|(t0<<1)|e ; cell = s>>1
    const int cR = ((t>>4)<<7) | (t & 15);
    #pragma unroll
    for (int k = 0; k < 8; ++k) {
        const float4 v = ldsc[cR | (k<<4)];
        a[2*k]   = (v2f){v.x, v.y};
        a[2*k+1] = (v2f){v.z, v.w};
    }
    // S2: reg amp-bits {7,6,5} = k
    RG(3, 8) RG(4, 4) RG(5, 2)
    __syncthreads();   // bar3: all X1 reads done before h-scattered writes

    // X2 write, perm-folded: amp s -> LDS slot h(s), so LDS[o] = V[g(o)].
    // cell = h(s_e0)>>1 ; intra-cell order swaps when parity(s_e0) is odd.
    {
        const int sB    = (((t>>4)&7)<<8) | (((t>>1)&7)<<2) | ((t&1)<<1);
        const int cellB = hperm(sB) >> 1;
        const int pt    = __popc(t) & 1;
        #pragma unroll
        for (int k = 0; k < 8; ++k) {
            const int cell = cellB ^ (hperm(k<<5) >> 1);   // constexpr k-part
            const bool sw  = (pt ^ (__popc(k) & 1)) != 0;
            const v2f lo = sw ? a[2*k+1] : a[2*k];
            const v2f hi = sw ? a[2*k]   : a[2*k+1];
            ldsc[cell] = make_float4(lo.x, lo.y, hi.x, hi.y);
        }
    }
    __syncthreads();   // bar4

    // X2 read, linear: a[2k+e] = V[g(o)], o = (k<<8)|(t<<1)|e
    #pragma unroll
    for (int k = 0; k < 8; ++k) {
        const float4 v = ldsc[(k<<7) | t];
        a[2*k]   = (v2f){v.x, v.y};
        a[2*k+1] = (v2f){v.z, v.w};
    }

    // S3: q6..q9 conjugated through g: o-masks 31,15,7,3 ->
    // lane-xor {15,7,3,1} (DPP 0x140,0x141,27,177) + e-swap; role = o_b^o_{b+1}
    CGD(6, 0x140, ((t>>3) ^ (t>>4)) & 1)
    CGD(7, 0x141, ((t>>2) ^ (t>>3)) & 1)
    CGD(8, 27,    ((t>>1) ^ (t>>2)) & 1)
    CGD(9, 177,   ( t     ^ (t>>1)) & 1)

    // store: cell (k<<7)|t -> 1KB/wave contiguous bursts
    float4* o = out4 + (size_t)b * (DIM/2);
    #pragma unroll
    for (int k = 0; k < 8; ++k)
        o[(k<<7) | t] = make_float4(a[2*k].x, a[2*k].y, a[2*k+1].x, a[2*k+1].y);
    #undef RG
    #undef CGD
}

extern "C" void kernel_launch(void* const* d_in, const int* in_sizes, int n_in,
                              void* d_out, int out_size, void* d_ws, size_t ws_size,
                              hipStream_t stream) {
    const float* X = (const float*)d_in[0];   // (B, NQ) float32
    const float* P = (const float*)d_in[1];   // (NL, NQ, 3) float32
    float2* ws  = (float2*)d_ws;              // 16 KB shared state (16B-aligned)
    const int B = in_sizes[0] / NQ;           // 8192
    qnn_shared_kernel<<<1, 256, 0, stream>>>(P, ws);
    qnn_last_kernel<<<B, 128, 0, stream>>>(X, (const float4*)ws, (float4*)d_out);
}